// Round 14
// baseline (340.264 us; speedup 1.0000x reference)
//
#include <hip/hip_runtime.h>
#include <hip/hip_fp16.h>

#define N_NODES 100000
#define N_PAIRS 1600000
#define EDGE_NUM 30000
#define D 64
#define NEG_SLOPE 0.2f
#define TN 16    // nodes staged per block in x0 gemm

#define CAP_E 128        // max slots per edge key   (mean deg 53.3, Poisson)
#define CAP_V 64         // max slots per vertex key (mean deg 16)
#define NGF 128          // pair-chunks per XCD group in pinned fills
#define FBLK (8 * NGF)   // fill blocks per side
#define XBLK2 1024       // fused x0 blocks

typedef int iv4 __attribute__((ext_vector_type(4)));

// ===========================================================================
// x0 GEMM body + fp16-X emission (K2 gathers from X16 at half the bytes)
// ===========================================================================
__device__ __forceinline__ void x0_body(
    const float* __restrict__ X, const float* __restrict__ Ww,
    const float* __restrict__ Wb, float* __restrict__ out0,
    __half* __restrict__ X16, int bid, int nblk, float (*xs)[D])
{
    const int wave = threadIdx.x >> 6;
    const int lane = threadIdx.x & 63;

    float w[64];
    const float* wrow = Ww + (size_t)lane * 64;
    #pragma unroll
    for (int i = 0; i < 64; i += 4) {
        float4 v = *(const float4*)(wrow + i);
        w[i] = v.x; w[i+1] = v.y; w[i+2] = v.z; w[i+3] = v.w;
    }
    const float b = Wb[lane];

    for (int base = bid * TN; base < N_NODES; base += nblk * TN) {
        const int ntile = min(TN, N_NODES - base);
        __syncthreads();
        {
            int n = threadIdx.x >> 4;
            int c = (threadIdx.x & 15) << 2;
            if (n < ntile) {
                float4 v = *(const float4*)&X[(size_t)(base + n) * D + c];
                *(float4*)&xs[n][c] = v;
                __half2* hdst = (__half2*)(X16 + (size_t)(base + n) * D + c);
                hdst[0] = __floats2half2_rn(v.x, v.y);
                hdst[1] = __floats2half2_rn(v.z, v.w);
            }
        }
        __syncthreads();
        #pragma unroll
        for (int q = 0; q < 4; ++q) {
            const int n = wave * 4 + q;
            if (n < ntile) {
                float acc = 0.f;
                #pragma unroll
                for (int i = 0; i < 64; ++i) acc = fmaf(xs[n][i], w[i], acc);
                out0[(size_t)(base + n) * D + lane] = acc + b;
            }
        }
    }
}

// ===========================================================================
// K1: e-side pinned bucket fill (R14: int4-quad, 4 atomics in flight/thread)
//     + fused x0 (+X16 emission)
// ===========================================================================
__global__ __launch_bounds__(256) void fillE_x0_kernel(
    const int* __restrict__ edges, const int* __restrict__ vertex,
    int* __restrict__ ecnt, int* __restrict__ evb,
    const float* __restrict__ X, const float* __restrict__ Ww,
    const float* __restrict__ Wb, float* __restrict__ out0,
    __half* __restrict__ X16)
{
    if (blockIdx.x < FBLK) {
        const int xcd = blockIdx.x & 7;
        const int grp = blockIdx.x >> 3;           // 0..NGF-1
        const int elo = xcd * (EDGE_NUM / 8);
        const int ehi = elo + (EDGE_NUM / 8);
        const int tid = grp * 256 + threadIdx.x;
        for (int i0 = tid * 4; i0 < N_PAIRS; i0 += NGF * 256 * 4) {
            const iv4 e4 = *(const iv4*)(edges + i0);
            const iv4 v4 = *(const iv4*)(vertex + i0);
            int s[4];
            #pragma unroll
            for (int u = 0; u < 4; ++u)
                s[u] = (e4[u] >= elo && e4[u] < ehi)
                         ? atomicAdd(&ecnt[e4[u]], 1) : -1;
            #pragma unroll
            for (int u = 0; u < 4; ++u)
                if (s[u] >= 0 && s[u] < CAP_E)
                    evb[(size_t)e4[u] * CAP_E + s[u]] = v4[u];
        }
        return;
    }
    __shared__ float xs[TN][D];
    x0_body(X, Ww, Wb, out0, X16, blockIdx.x - FBLK, XBLK2, xs);
}

// ===========================================================================
// K2: v-side pinned fill (R14: int4-quad, u16 payloads) fused with per-edge
// gather reading fp16 X16 (128 B/row).
// ===========================================================================
__global__ __launch_bounds__(256) void fillV_edge_kernel(
    const int* __restrict__ edges, const int* __restrict__ vertex,
    int* __restrict__ vcnt, unsigned short* __restrict__ vvb,
    const __half* __restrict__ X16, const float* __restrict__ degV,
    const float* __restrict__ Ww, const float* __restrict__ Wb,
    const int* __restrict__ ecnt, const int* __restrict__ evb,
    __half* __restrict__ Xe)
{
    if (blockIdx.x < FBLK) {
        const int xcd = blockIdx.x & 7;
        const int grp = blockIdx.x >> 3;           // 0..NGF-1
        const int vlo = xcd * (N_NODES / 8);
        const int vhi = vlo + (N_NODES / 8);
        const int tid = grp * 256 + threadIdx.x;
        for (int i0 = tid * 4; i0 < N_PAIRS; i0 += NGF * 256 * 4) {
            const iv4 e4 = *(const iv4*)(edges + i0);
            const iv4 v4 = *(const iv4*)(vertex + i0);
            int s[4];
            #pragma unroll
            for (int u = 0; u < 4; ++u)
                s[u] = (v4[u] >= vlo && v4[u] < vhi)
                         ? atomicAdd(&vcnt[v4[u]], 1) : -1;
            #pragma unroll
            for (int u = 0; u < 4; ++u)
                if (s[u] >= 0 && s[u] < CAP_V)
                    vvb[(size_t)v4[u] * CAP_V + s[u]] = (unsigned short)e4[u];
        }
        return;
    }

    // ---- edge gather part (R2-proven structure: LDS W, 8-wide unroll) ----
    __shared__ float Wlds[64 * 65];
    __shared__ float aLds[4][64];
    const int lane = threadIdx.x & 63;
    const int wave = threadIdx.x >> 6;
    const int e = (blockIdx.x - FBLK) * 4 + wave;
    const int t = (e >= 10000) + (e >= 20000);   // uniform per block (%4==0)

    {
        const float* wsrc = Ww + (size_t)(t + 1) * 4096;
        for (int idx = threadIdx.x * 4; idx < 4096; idx += 256 * 4) {
            float4 v = *(const float4*)(wsrc + idx);
            const int r = idx >> 6, c = idx & 63;
            float* dst = &Wlds[r * 65 + c];
            dst[0] = v.x; dst[1] = v.y; dst[2] = v.z; dst[3] = v.w;
        }
    }
    __syncthreads();

    const float b = Wb[(t + 1) * 64 + lane];
    const int cntE = ecnt[e];
    const int mtot = min(cntE, CAP_E);
    const int* __restrict__ lst = evb + (size_t)e * CAP_E;
    const float* __restrict__ degt = degV + (size_t)t * N_NODES;
    const __half* __restrict__ Xl = X16 + lane;

    float acc0 = 0.f, acc1 = 0.f, sdeg = 0.f;
    for (int j0 = 0; j0 < mtot; j0 += 64) {
        const int m = min(64, mtot - j0);
        const int vv = (lane < m) ? lst[j0 + lane] : 0;
        int j = 0;
        for (; j + 8 <= m; j += 8) {
            int v[8];
            #pragma unroll
            for (int u = 0; u < 8; ++u) v[u] = __shfl(vv, j + u);
            float f[8], s[8];
            #pragma unroll
            for (int u = 0; u < 8; ++u) f[u] = __half2float(Xl[(size_t)v[u] * D]);
            #pragma unroll
            for (int u = 0; u < 8; ++u) s[u] = degt[v[u]];
            #pragma unroll
            for (int u = 0; u < 8; u += 2) {
                acc0 = fmaf(s[u],     f[u],     acc0);
                acc1 = fmaf(s[u + 1], f[u + 1], acc1);
                sdeg += s[u] + s[u + 1];
            }
        }
        for (; j < m; ++j) {
            const int v = __shfl(vv, j);
            const float s = degt[v];
            acc0 = fmaf(s, __half2float(Xl[(size_t)v * D]), acc0);
            sdeg += s;
        }
    }
    aLds[wave][lane] = acc0 + acc1;

    float r = 0.f;
    #pragma unroll
    for (int i = 0; i < 64; ++i)
        r = fmaf(aLds[wave][i], Wlds[lane * 65 + i], r);
    r += sdeg * b;
    const int k = max(cntE, 1);
    Xe[(size_t)e * D + lane] = __float2half(r / (float)k);
}

// ===========================================================================
// K3: per-vertex gather, XCD-pinned to match fillV's vertex partition (R14):
// block (xcd,grp) handles v in [xcd*12500 + grp*4, +4) -> vvb dirty lines are
// local-L2 hits instead of cross-XCD snoops.
// ===========================================================================
__global__ __launch_bounds__(256) void vertex_gather_bkt_kernel(
    const __half* __restrict__ Xe, const int* __restrict__ vcnt,
    const unsigned short* __restrict__ vvb, float* __restrict__ out)
{
    const int xcd = blockIdx.x & 7;
    const int grp = blockIdx.x >> 3;               // 0..3124
    const int v = xcd * (N_NODES / 8) + grp * 4 + (threadIdx.x >> 6);
    const int lane = threadIdx.x & 63;
    const int mtot = min(vcnt[v], CAP_V);
    const unsigned short* __restrict__ lst = vvb + (size_t)v * CAP_V;
    const __half* __restrict__ Xel = Xe + lane;

    float acc0 = out[(size_t)v * D + lane];   // X0
    float acc1 = 0.f;
    for (int j0 = 0; j0 < mtot; j0 += 64) {
        const int m = min(64, mtot - j0);
        const int ee = (lane < m) ? (int)lst[j0 + lane] : 0;
        int j = 0;
        for (; j + 8 <= m; j += 8) {
            int e[8];
            #pragma unroll
            for (int u = 0; u < 8; ++u) e[u] = __shfl(ee, j + u);
            float f[8];
            #pragma unroll
            for (int u = 0; u < 8; ++u)
                f[u] = __half2float(Xel[(size_t)e[u] * D]);
            #pragma unroll
            for (int u = 0; u < 8; u += 2) {
                acc0 += f[u];
                acc1 += f[u + 1];
            }
        }
        for (; j < m; ++j) {
            const int e = __shfl(ee, j);
            acc0 += __half2float(Xel[(size_t)e * D]);
        }
    }
    const float acc = acc0 + acc1;

    float ss = acc * acc;
    #pragma unroll
    for (int off = 1; off < 64; off <<= 1) ss += __shfl_xor(ss, off);
    const float rn = sqrtf(ss);
    const float scale = (rn == 0.f) ? 0.f : 1.f / rn;
    const float y = acc * scale;
    out[(size_t)v * D + lane] = (y > 0.f) ? y : NEG_SLOPE * y;
}

// ---------------------------------------------------------------------------
extern "C" void kernel_launch(void* const* d_in, const int* in_sizes, int n_in,
                              void* d_out, int out_size, void* d_ws, size_t ws_size,
                              hipStream_t stream)
{
    const float* X      = (const float*)d_in[0];   // (100000, 64)
    const float* degV   = (const float*)d_in[1];   // (3, 100000, 1)
    const float* Ww     = (const float*)d_in[2];   // (4, 64, 64)
    const float* Wb     = (const float*)d_in[3];   // (4, 64)
    const int*   vertex = (const int*)d_in[4];     // (1600000,)
    const int*   edges  = (const int*)d_in[5];     // (1600000,)
    float* out = (float*)d_out;                    // (100000, 64)

    // workspace (45.3 MB — R9 proved >=49.2 MB available):
    //   Xe   : 1,920,000 half  (3.84 MB)
    //   X16  : 6,400,000 half  (12.8 MB)
    //   ints : ecnt 30016 + vcnt 100016 (0.52 MB)
    //   evb  : 30000*128 int   (15.36 MB)
    //   vvb  : 100000*64 u16   (12.8 MB)
    __half* Xe  = (__half*)d_ws;
    __half* X16 = Xe + 1920000;
    int* ib    = (int*)(X16 + 6400000);
    int* ecnt  = ib;
    int* vcnt  = ib + 30016;
    int* evb   = ib + 130032;
    unsigned short* vvb = (unsigned short*)(evb + (size_t)EDGE_NUM * CAP_E);

    hipMemsetAsync(ib, 0, (size_t)130032 * sizeof(int), stream);

    // K1: e-side fill (blocks 0..1023) + x0/X16 (blocks 1024..2047), concurrent
    fillE_x0_kernel<<<FBLK + XBLK2, 256, 0, stream>>>(
        edges, vertex, ecnt, evb, X, Ww, Wb, out, X16);

    // K2: v-side fill (u16) + edge gather (fp16 X16 reads, fp16 Xe writes)
    fillV_edge_kernel<<<FBLK + EDGE_NUM / 4, 256, 0, stream>>>(
        edges, vertex, vcnt, vvb, X16, degV, Ww, Wb, ecnt, evb, Xe);

    // K3: vertex gather (XCD-pinned, fp16 Xe, u16 lists) + X0 + norm + lrelu
    vertex_gather_bkt_kernel<<<N_NODES / 4, 256, 0, stream>>>(
        Xe, vcnt, vvb, out);
}

// Round 15
// 334.103 us; speedup vs baseline: 1.0184x; 1.0184x over previous
//
#include <hip/hip_runtime.h>
#include <hip/hip_fp16.h>

#define N_NODES 100000
#define N_PAIRS 1600000
#define EDGE_NUM 30000
#define D 64
#define NEG_SLOPE 0.2f
#define TN 16    // nodes staged per block in x0 gemm

#define CAP_E 128        // max slots per edge key   (mean deg 53.3, max~86)
#define CAP_V 48         // max slots per vertex key (mean 16, max~35; 8-sigma)
#define NGF 128          // pair-chunks per XCD group in pinned fills
#define FBLK (8 * NGF)   // fill blocks per side
#define XBLK2 1024       // fused x0 blocks
#define PPBLK 256        // prepack blocks (pack v<<15|e into u32)

typedef int iv4 __attribute__((ext_vector_type(4)));
typedef unsigned int uv4 __attribute__((ext_vector_type(4)));

// ===========================================================================
// x0 GEMM body + fp16-X emission (K2 gathers from X16 at half the bytes)
// ===========================================================================
__device__ __forceinline__ void x0_body(
    const float* __restrict__ X, const float* __restrict__ Ww,
    const float* __restrict__ Wb, float* __restrict__ out0,
    __half* __restrict__ X16, int bid, int nblk, float (*xs)[D])
{
    const int wave = threadIdx.x >> 6;
    const int lane = threadIdx.x & 63;

    float w[64];
    const float* wrow = Ww + (size_t)lane * 64;
    #pragma unroll
    for (int i = 0; i < 64; i += 4) {
        float4 v = *(const float4*)(wrow + i);
        w[i] = v.x; w[i+1] = v.y; w[i+2] = v.z; w[i+3] = v.w;
    }
    const float b = Wb[lane];

    for (int base = bid * TN; base < N_NODES; base += nblk * TN) {
        const int ntile = min(TN, N_NODES - base);
        __syncthreads();
        {
            int n = threadIdx.x >> 4;
            int c = (threadIdx.x & 15) << 2;
            if (n < ntile) {
                float4 v = *(const float4*)&X[(size_t)(base + n) * D + c];
                *(float4*)&xs[n][c] = v;
                __half2* hdst = (__half2*)(X16 + (size_t)(base + n) * D + c);
                hdst[0] = __floats2half2_rn(v.x, v.y);
                hdst[1] = __floats2half2_rn(v.z, v.w);
            }
        }
        __syncthreads();
        #pragma unroll
        for (int q = 0; q < 4; ++q) {
            const int n = wave * 4 + q;
            if (n < ntile) {
                float acc = 0.f;
                #pragma unroll
                for (int i = 0; i < 64; ++i) acc = fmaf(xs[n][i], w[i], acc);
                out0[(size_t)(base + n) * D + lane] = acc + b;
            }
        }
    }
}

// ===========================================================================
// K1: e-side pinned bucket fill (R13 scalar form — R14 int4 refuted)
//     + fused x0/X16 + R15 prepack blocks (pack (v,e) into one u32)
// ===========================================================================
__global__ __launch_bounds__(256) void fillE_x0_kernel(
    const int* __restrict__ edges, const int* __restrict__ vertex,
    int* __restrict__ ecnt, int* __restrict__ evb,
    const float* __restrict__ X, const float* __restrict__ Ww,
    const float* __restrict__ Wb, float* __restrict__ out0,
    __half* __restrict__ X16, unsigned int* __restrict__ packed)
{
    if (blockIdx.x < FBLK) {
        const int xcd = blockIdx.x & 7;
        const int grp = blockIdx.x >> 3;           // 0..NGF-1
        const int elo = xcd * (EDGE_NUM / 8);
        const int ehi = elo + (EDGE_NUM / 8);
        for (int i = grp * 256 + threadIdx.x; i < N_PAIRS; i += NGF * 256) {
            const int e = edges[i];
            if (e >= elo && e < ehi) {
                const int s = atomicAdd(&ecnt[e], 1);
                if (s < CAP_E) evb[(size_t)e * CAP_E + s] = vertex[i];
            }
        }
        return;
    }
    if (blockIdx.x >= FBLK + XBLK2) {
        // prepack: packed[i] = (v << 15) | e  (v<2^17, e<2^15 -> exactly 32b)
        const int bid = blockIdx.x - FBLK - XBLK2;   // 0..PPBLK-1
        for (int i0 = (bid * 256 + threadIdx.x) * 4; i0 < N_PAIRS;
             i0 += PPBLK * 256 * 4) {
            const iv4 e4 = *(const iv4*)(edges + i0);
            const iv4 v4 = *(const iv4*)(vertex + i0);
            uv4 p4;
            #pragma unroll
            for (int u = 0; u < 4; ++u)
                p4[u] = ((unsigned int)v4[u] << 15) | (unsigned int)e4[u];
            *(uv4*)(packed + i0) = p4;
        }
        return;
    }
    __shared__ float xs[TN][D];
    x0_body(X, Ww, Wb, out0, X16, blockIdx.x - FBLK, XBLK2, xs);
}

// ===========================================================================
// K2: v-side pinned fill reading packed u32 (R15: one load/pair instead of
// two) fused with per-edge gather reading fp16 X16 (128 B/row).
// ===========================================================================
__global__ __launch_bounds__(256) void fillV_edge_kernel(
    const unsigned int* __restrict__ packed,
    int* __restrict__ vcnt, unsigned short* __restrict__ vvb,
    const __half* __restrict__ X16, const float* __restrict__ degV,
    const float* __restrict__ Ww, const float* __restrict__ Wb,
    const int* __restrict__ ecnt, const int* __restrict__ evb,
    __half* __restrict__ Xe)
{
    if (blockIdx.x < FBLK) {
        const int xcd = blockIdx.x & 7;
        const int grp = blockIdx.x >> 3;           // 0..NGF-1
        const int vlo = xcd * (N_NODES / 8);
        const int vhi = vlo + (N_NODES / 8);
        for (int i = grp * 256 + threadIdx.x; i < N_PAIRS; i += NGF * 256) {
            const unsigned int pk = packed[i];
            const int v = (int)(pk >> 15);
            if (v >= vlo && v < vhi) {
                const int s = atomicAdd(&vcnt[v], 1);
                if (s < CAP_V)
                    vvb[(size_t)v * CAP_V + s] =
                        (unsigned short)(pk & 0x7FFFu);
            }
        }
        return;
    }

    // ---- edge gather part (R2-proven structure: LDS W, 8-wide unroll) ----
    __shared__ float Wlds[64 * 65];
    __shared__ float aLds[4][64];
    const int lane = threadIdx.x & 63;
    const int wave = threadIdx.x >> 6;
    const int e = (blockIdx.x - FBLK) * 4 + wave;
    const int t = (e >= 10000) + (e >= 20000);   // uniform per block (%4==0)

    {
        const float* wsrc = Ww + (size_t)(t + 1) * 4096;
        for (int idx = threadIdx.x * 4; idx < 4096; idx += 256 * 4) {
            float4 v = *(const float4*)(wsrc + idx);
            const int r = idx >> 6, c = idx & 63;
            float* dst = &Wlds[r * 65 + c];
            dst[0] = v.x; dst[1] = v.y; dst[2] = v.z; dst[3] = v.w;
        }
    }
    __syncthreads();

    const float b = Wb[(t + 1) * 64 + lane];
    const int cntE = ecnt[e];
    const int mtot = min(cntE, CAP_E);
    const int* __restrict__ lst = evb + (size_t)e * CAP_E;
    const float* __restrict__ degt = degV + (size_t)t * N_NODES;
    const __half* __restrict__ Xl = X16 + lane;

    float acc0 = 0.f, acc1 = 0.f, sdeg = 0.f;
    for (int j0 = 0; j0 < mtot; j0 += 64) {
        const int m = min(64, mtot - j0);
        const int vv = (lane < m) ? lst[j0 + lane] : 0;
        int j = 0;
        for (; j + 8 <= m; j += 8) {
            int v[8];
            #pragma unroll
            for (int u = 0; u < 8; ++u) v[u] = __shfl(vv, j + u);
            float f[8], s[8];
            #pragma unroll
            for (int u = 0; u < 8; ++u) f[u] = __half2float(Xl[(size_t)v[u] * D]);
            #pragma unroll
            for (int u = 0; u < 8; ++u) s[u] = degt[v[u]];
            #pragma unroll
            for (int u = 0; u < 8; u += 2) {
                acc0 = fmaf(s[u],     f[u],     acc0);
                acc1 = fmaf(s[u + 1], f[u + 1], acc1);
                sdeg += s[u] + s[u + 1];
            }
        }
        for (; j < m; ++j) {
            const int v = __shfl(vv, j);
            const float s = degt[v];
            acc0 = fmaf(s, __half2float(Xl[(size_t)v * D]), acc0);
            sdeg += s;
        }
    }
    aLds[wave][lane] = acc0 + acc1;

    float r = 0.f;
    #pragma unroll
    for (int i = 0; i < 64; ++i)
        r = fmaf(aLds[wave][i], Wlds[lane * 65 + i], r);
    r += sdeg * b;
    const int k = max(cntE, 1);
    Xe[(size_t)e * D + lane] = __float2half(r / (float)k);
}

// ===========================================================================
// K3: per-vertex gather (fp16 Xe, u16 lists, R13 unpinned form) + X0 add +
// normalize + leaky relu
// ===========================================================================
__global__ __launch_bounds__(256) void vertex_gather_bkt_kernel(
    const __half* __restrict__ Xe, const int* __restrict__ vcnt,
    const unsigned short* __restrict__ vvb, float* __restrict__ out)
{
    const int v = blockIdx.x * 4 + (threadIdx.x >> 6);
    const int lane = threadIdx.x & 63;
    const int mtot = min(vcnt[v], CAP_V);
    const unsigned short* __restrict__ lst = vvb + (size_t)v * CAP_V;
    const __half* __restrict__ Xel = Xe + lane;

    float acc0 = out[(size_t)v * D + lane];   // X0
    float acc1 = 0.f;
    for (int j0 = 0; j0 < mtot; j0 += 64) {
        const int m = min(64, mtot - j0);
        const int ee = (lane < m) ? (int)lst[j0 + lane] : 0;
        int j = 0;
        for (; j + 8 <= m; j += 8) {
            int e[8];
            #pragma unroll
            for (int u = 0; u < 8; ++u) e[u] = __shfl(ee, j + u);
            float f[8];
            #pragma unroll
            for (int u = 0; u < 8; ++u)
                f[u] = __half2float(Xel[(size_t)e[u] * D]);
            #pragma unroll
            for (int u = 0; u < 8; u += 2) {
                acc0 += f[u];
                acc1 += f[u + 1];
            }
        }
        for (; j < m; ++j) {
            const int e = __shfl(ee, j);
            acc0 += __half2float(Xel[(size_t)e * D]);
        }
    }
    const float acc = acc0 + acc1;

    float ss = acc * acc;
    #pragma unroll
    for (int off = 1; off < 64; off <<= 1) ss += __shfl_xor(ss, off);
    const float rn = sqrtf(ss);
    const float scale = (rn == 0.f) ? 0.f : 1.f / rn;
    const float y = acc * scale;
    out[(size_t)v * D + lane] = (y > 0.f) ? y : NEG_SLOPE * y;
}

// ---------------------------------------------------------------------------
extern "C" void kernel_launch(void* const* d_in, const int* in_sizes, int n_in,
                              void* d_out, int out_size, void* d_ws, size_t ws_size,
                              hipStream_t stream)
{
    const float* X      = (const float*)d_in[0];   // (100000, 64)
    const float* degV   = (const float*)d_in[1];   // (3, 100000, 1)
    const float* Ww     = (const float*)d_in[2];   // (4, 64, 64)
    const float* Wb     = (const float*)d_in[3];   // (4, 64)
    const int*   vertex = (const int*)d_in[4];     // (1600000,)
    const int*   edges  = (const int*)d_in[5];     // (1600000,)
    float* out = (float*)d_out;                    // (100000, 64)

    // workspace (48.5 MB — R9 proved >=49.2 MB available):
    //   Xe     : 1,920,000 half (3.84 MB)
    //   X16    : 6,400,000 half (12.8 MB)
    //   ints   : ecnt 30016 + vcnt 100016 (0.52 MB)
    //   evb    : 30000*128 int  (15.36 MB)
    //   packed : 1,600,000 u32  (6.4 MB)    v<<15 | e
    //   vvb    : 100000*48 u16  (9.6 MB)
    __half* Xe  = (__half*)d_ws;
    __half* X16 = Xe + 1920000;
    int* ib    = (int*)(X16 + 6400000);
    int* ecnt  = ib;
    int* vcnt  = ib + 30016;
    int* evb   = ib + 130032;
    unsigned int* packed = (unsigned int*)(evb + (size_t)EDGE_NUM * CAP_E);
    unsigned short* vvb  = (unsigned short*)(packed + N_PAIRS);

    hipMemsetAsync(ib, 0, (size_t)130032 * sizeof(int), stream);

    // K1: e-fill (0..1023) + x0/X16 (1024..2047) + prepack (2048..2303)
    fillE_x0_kernel<<<FBLK + XBLK2 + PPBLK, 256, 0, stream>>>(
        edges, vertex, ecnt, evb, X, Ww, Wb, out, X16, packed);

    // K2: v-fill (packed u32 reads, u16 stores) + edge gather (fp16)
    fillV_edge_kernel<<<FBLK + EDGE_NUM / 4, 256, 0, stream>>>(
        packed, vcnt, vvb, X16, degV, Ww, Wb, ecnt, evb, Xe);

    // K3: vertex gather (fp16 Xe, u16 lists) + X0 + normalize + leaky relu
    vertex_gather_bkt_kernel<<<N_NODES / 4, 256, 0, stream>>>(
        Xe, vcnt, vvb, out);
}